// Round 1
// baseline (411.645 us; speedup 1.0000x reference)
//
#include <hip/hip_runtime.h>
#include <hip/hip_bf16.h>

#define IN_F   4096
#define OUT_F  4096
#define GROUP  128
#define PACKED (IN_F / 8)      // 512
#define M_DIM  8192            // 4 * 2048
#define N_DIM  OUT_F
#define K_DIM  IN_F

typedef __bf16 bf16x8 __attribute__((ext_vector_type(8)));
typedef float  f32x4  __attribute__((ext_vector_type(4)));

// ---------------------------------------------------------------------------
// Pre-pass 1: dequantize int4 -> bf16, W[N][K] row-major (B^T layout).
// One thread per packed int32 (8 nibbles -> 8 bf16, 16B vector store).
// ---------------------------------------------------------------------------
__global__ __launch_bounds__(256) void dequant_kernel(
    const int* __restrict__ qw, const float* __restrict__ qs,
    const int* __restrict__ qz, __bf16* __restrict__ W)
{
    int t = blockIdx.x * blockDim.x + threadIdx.x;   // 0 .. OUT_F*PACKED-1
    if (t >= OUT_F * PACKED) return;
    int o = t >> 9;           // / PACKED
    int c = t & (PACKED - 1);
    int g = c >> 4;           // group = (c*8)/128 = c/16
    unsigned int q = (unsigned int)qw[t];
    float scale = qs[g * OUT_F + o];
    float zero  = (float)qz[g * OUT_F + o];
    bf16x8 v;
#pragma unroll
    for (int i = 0; i < 8; ++i) {
        float wi = (float)((q >> (4 * i)) & 15u);
        v[i] = (__bf16)((wi - zero) * scale);
    }
    *reinterpret_cast<bf16x8*>(&W[(size_t)t * 8]) = v;
}

// ---------------------------------------------------------------------------
// Pre-pass 2: x f32 -> bf16 (RNE), 8 elements/thread.
// ---------------------------------------------------------------------------
__global__ __launch_bounds__(256) void cvt_kernel(
    const float* __restrict__ x, __bf16* __restrict__ xb, int n8)
{
    int t = blockIdx.x * blockDim.x + threadIdx.x;
    if (t >= n8) return;
    const float4* xv = reinterpret_cast<const float4*>(x);
    float4 a = xv[2 * t];
    float4 b = xv[2 * t + 1];
    bf16x8 v;
    v[0] = (__bf16)a.x; v[1] = (__bf16)a.y; v[2] = (__bf16)a.z; v[3] = (__bf16)a.w;
    v[4] = (__bf16)b.x; v[5] = (__bf16)b.y; v[6] = (__bf16)b.z; v[7] = (__bf16)b.w;
    reinterpret_cast<bf16x8*>(xb)[t] = v;
}

// ---------------------------------------------------------------------------
// GEMM: C[M][N] = A[M][K] * B[N][K]^T, bf16 inputs, f32 accumulate.
// 128x128 tile, BK=64, 4 waves (2x2), 64x64 per wave, mfma_f32_16x16x32_bf16.
// global_load_lds width=16 staging, single-buffer 2-barrier K loop (m97).
// ---------------------------------------------------------------------------
__global__ __launch_bounds__(256) void gemm_kernel(
    const __bf16* __restrict__ A, const __bf16* __restrict__ B,
    float* __restrict__ C)
{
    __shared__ __bf16 As[128][64];
    __shared__ __bf16 Bs[128][64];

    const int tid  = threadIdx.x;
    const int lane = tid & 63;
    const int wave = tid >> 6;
    const int mBase = blockIdx.y * 128;
    const int nBase = blockIdx.x * 128;
    const int wm = (wave >> 1) * 64;   // wave row offset within tile
    const int wn = (wave &  1) * 64;   // wave col offset within tile
    const int frow = lane & 15;        // fragment row (A) / col (B)
    const int koff = (lane >> 4) * 8;  // k sub-offset within 32

    f32x4 acc[4][4];
#pragma unroll
    for (int i = 0; i < 4; ++i)
#pragma unroll
        for (int j = 0; j < 4; ++j)
            acc[i][j] = 0.0f;

    for (int k0 = 0; k0 < K_DIM; k0 += 64) {
        // stage A-tile and B-tile: 128x64 bf16 = 16 KB each; 4 issues x 256
        // threads x 16 B. LDS dest is linear in lane order (wave-uniform
        // base + lane*16) as global_load_lds requires.
#pragma unroll
        for (int s = 0; s < 4; ++s) {
            int idx = tid + s * 256;        // 0..1023
            int r = idx >> 3;               // 0..127
            int c = (idx & 7) << 3;         // 0,8,..,56
            __builtin_amdgcn_global_load_lds(
                (const __attribute__((address_space(1))) void*)(A + (size_t)(mBase + r) * K_DIM + (k0 + c)),
                (__attribute__((address_space(3))) void*)&As[r][c], 16, 0, 0);
            __builtin_amdgcn_global_load_lds(
                (const __attribute__((address_space(1))) void*)(B + (size_t)(nBase + r) * K_DIM + (k0 + c)),
                (__attribute__((address_space(3))) void*)&Bs[r][c], 16, 0, 0);
        }
        __syncthreads();

#pragma unroll
        for (int kk = 0; kk < 64; kk += 32) {
            bf16x8 af[4], bq[4];
#pragma unroll
            for (int i = 0; i < 4; ++i)
                af[i] = *reinterpret_cast<const bf16x8*>(&As[wm + i * 16 + frow][kk + koff]);
#pragma unroll
            for (int j = 0; j < 4; ++j)
                bq[j] = *reinterpret_cast<const bf16x8*>(&Bs[wn + j * 16 + frow][kk + koff]);
#pragma unroll
            for (int i = 0; i < 4; ++i)
#pragma unroll
                for (int j = 0; j < 4; ++j)
                    acc[i][j] = __builtin_amdgcn_mfma_f32_16x16x32_bf16(af[i], bq[j], acc[i][j], 0, 0, 0);
        }
        __syncthreads();
    }

    // Epilogue: C/D layout col=lane&15, row=(lane>>4)*4+reg (m89-verified).
    // Mimic reference: y computed in bf16 then upcast to f32.
    const int rgrp = (lane >> 4) * 4;
    const int ccol = lane & 15;
#pragma unroll
    for (int i = 0; i < 4; ++i) {
#pragma unroll
        for (int j = 0; j < 4; ++j) {
            int col = nBase + wn + j * 16 + ccol;
#pragma unroll
            for (int r = 0; r < 4; ++r) {
                int row = mBase + wm + i * 16 + rgrp + r;
                C[(size_t)row * N_DIM + col] = (float)(__bf16)acc[i][j][r];
            }
        }
    }
}

extern "C" void kernel_launch(void* const* d_in, const int* in_sizes, int n_in,
                              void* d_out, int out_size, void* d_ws, size_t ws_size,
                              hipStream_t stream)
{
    const float* x       = (const float*)d_in[0];
    const int*   qweight = (const int*)d_in[1];
    const float* qscale  = (const float*)d_in[2];
    const int*   qzeros  = (const int*)d_in[3];
    float*       out     = (float*)d_out;

    // workspace layout: W bf16 [N][K] (32 MB), then x bf16 [M][K] (64 MB)
    __bf16* W  = (__bf16*)d_ws;
    __bf16* xb = (__bf16*)((char*)d_ws + (size_t)N_DIM * K_DIM * sizeof(__bf16));

    // 1) dequantize weights
    {
        int total = OUT_F * PACKED;            // 2,097,152
        dequant_kernel<<<(total + 255) / 256, 256, 0, stream>>>(qweight, qscale, qzeros, W);
    }
    // 2) convert activations
    {
        int n8 = (M_DIM * K_DIM) / 8;          // 4,194,304
        cvt_kernel<<<(n8 + 255) / 256, 256, 0, stream>>>(x, xb, n8);
    }
    // 3) GEMM
    {
        dim3 grid(N_DIM / 128, M_DIM / 128);   // 32 x 64
        gemm_kernel<<<grid, 256, 0, stream>>>(xb, W, out);
    }
}

// Round 2
// 303.493 us; speedup vs baseline: 1.3564x; 1.3564x over previous
//
#include <hip/hip_runtime.h>
#include <hip/hip_bf16.h>

#define IN_F   4096
#define OUT_F  4096
#define PACKED (IN_F / 8)      // 512
#define M_DIM  8192            // 4 * 2048
#define N_DIM  OUT_F
#define K_DIM  IN_F

#define BM 256
#define BN 256
#define BK 64
#define NT (K_DIM / BK)        // 64 K-tiles
#define NHALF (4 * NT)         // 256 half-tiles

typedef __bf16 bf16x8 __attribute__((ext_vector_type(8)));
typedef float  f32x4  __attribute__((ext_vector_type(4)));

#define BAR() asm volatile("s_barrier" ::: "memory")

// ---------------------------------------------------------------------------
// Pre-pass 1: dequantize int4 -> bf16, W[N][K] row-major (B^T layout).
// ---------------------------------------------------------------------------
__global__ __launch_bounds__(256) void dequant_kernel(
    const int* __restrict__ qw, const float* __restrict__ qs,
    const int* __restrict__ qz, __bf16* __restrict__ W)
{
    int t = blockIdx.x * blockDim.x + threadIdx.x;
    if (t >= OUT_F * PACKED) return;
    int o = t >> 9;
    int c = t & (PACKED - 1);
    int g = c >> 4;
    unsigned int q = (unsigned int)qw[t];
    float scale = qs[g * OUT_F + o];
    float zero  = (float)qz[g * OUT_F + o];
    bf16x8 v;
#pragma unroll
    for (int i = 0; i < 8; ++i) {
        float wi = (float)((q >> (4 * i)) & 15u);
        v[i] = (__bf16)((wi - zero) * scale);
    }
    *reinterpret_cast<bf16x8*>(&W[(size_t)t * 8]) = v;
}

// ---------------------------------------------------------------------------
// Pre-pass 2: x f32 -> bf16 (RNE), 8 elements/thread.
// ---------------------------------------------------------------------------
__global__ __launch_bounds__(256) void cvt_kernel(
    const float* __restrict__ x, __bf16* __restrict__ xb, int n8)
{
    int t = blockIdx.x * blockDim.x + threadIdx.x;
    if (t >= n8) return;
    const float4* xv = reinterpret_cast<const float4*>(x);
    float4 a = xv[2 * t];
    float4 b = xv[2 * t + 1];
    bf16x8 v;
    v[0] = (__bf16)a.x; v[1] = (__bf16)a.y; v[2] = (__bf16)a.z; v[3] = (__bf16)a.w;
    v[4] = (__bf16)b.x; v[5] = (__bf16)b.y; v[6] = (__bf16)b.z; v[7] = (__bf16)b.w;
    reinterpret_cast<bf16x8*>(xb)[t] = v;
}

// ---------------------------------------------------------------------------
// GEMM: 256x256 tile, BK=64, 8 waves (2Mx4N), 8-phase schedule (4 phases per
// K-tile x 2 K-tiles per dbuf cycle), counted vmcnt(6), setprio around MFMA.
// LDS: fragment-ordered 16x32 subtiles (1024B), zero-conflict ds_read_b128.
//   subtile st of a 256x64 tile: rows (st>>1)*16..+15, cols (st&1)*32..+31
//   within subtile, lane l holds bytes [l*16, l*16+16) =
//     elem[row = (l&15)][k = (l>>4)*8 .. +8)   (MFMA A/B fragment order)
// ---------------------------------------------------------------------------
__global__ __launch_bounds__(512, 2) void gemm_kernel(
    const __bf16* __restrict__ A, const __bf16* __restrict__ B,
    float* __restrict__ C)
{
    extern __shared__ __bf16 lds[];   // 2 bufs x (A 16384 + B 16384) elems = 128 KiB

    const int tid  = threadIdx.x;
    const int lane = tid & 63;
    const int wave = tid >> 6;        // 0..7
    const int wm   = wave >> 2;       // 0..1  (128-row block)
    const int wn   = wave & 3;        // 0..3  (64-col block)

    // bijective XCD swizzle: 512 blocks = 8 XCDs x 64
    const int bid = blockIdx.x;
    const int swz = (bid & 7) * 64 + (bid >> 3);
    const int nBase = (swz & 15) * BN;
    const int mBase = (swz >> 4) * BM;

    const int lr = lane & 15;         // fragment row (A) / col (B)
    const int lk = (lane >> 4) * 8;   // k sub-offset

    auto stage_half = [&](const __bf16* __restrict__ src, __bf16* dstMat,
                          int rowBase, int k0, int hh) {
#pragma unroll
        for (int i = 0; i < 2; ++i) {
            const int st = hh * 16 + i * 8 + wave;        // wave-uniform
            const int r  = (st >> 1) * 16 + lr;
            const int c  = (st & 1) * 32 + lk;
            __builtin_amdgcn_global_load_lds(
                (const __attribute__((address_space(1))) void*)(src + (size_t)(rowBase + r) * K_DIM + (k0 + c)),
                (__attribute__((address_space(3))) void*)(dstMat + st * 512 + lane * 8), 16, 0, 0);
        }
    };
    // half order per tile: 0=A-rows0-127, 1=A-rows128-255, 2=B-rows0-127, 3=B-rows128-255
    auto stage_H = [&](int H) {
        const int t = H >> 2;
        const int h = H & 3;
        __bf16* base = lds + (size_t)(t & 1) * 32768 + (size_t)(h >> 1) * 16384;
        if (h & 2) stage_half(B, base, nBase, t * BK, h & 1);
        else       stage_half(A, base, mBase, t * BK, h & 1);
    };

    f32x4 acc[8][4];
#pragma unroll
    for (int i = 0; i < 8; ++i)
#pragma unroll
        for (int j = 0; j < 4; ++j)
            acc[i][j] = 0.0f;

    // prologue: tile0 all 4 halves + tile1 halves A0,A1,B0 (B1 comes at t0/p0)
#pragma unroll
    for (int H = 0; H < 7; ++H) stage_H(H);
    asm volatile("s_waitcnt vmcnt(6)" ::: "memory");   // tile0 complete, 3 in flight
    BAR();

#define LDA(mi, kb) (*(const bf16x8*)(lA + (((wm * 8 + (mi)) * 2 + (kb)) * 512 + lane * 8)))
#define LDB(ni, kb) (*(const bf16x8*)(lB + (((wn * 4 + (ni)) * 2 + (kb)) * 512 + lane * 8)))

    for (int t = 0; t < NT; ++t) {
        const __bf16* lA = lds + (size_t)(t & 1) * 32768;
        const __bf16* lB = lA + 16384;
        const int Hb = 4 * t + 7;    // stage lead = +7 halves (3 half-tiles ahead)
        bf16x8 Af[8][2];
        bf16x8 Bf[2][2];

        // -- phase 0: read A mi0-3 + B ni0-1 (12 ds_read); stage (t+1,B1); MFMA Q0
#pragma unroll
        for (int mi = 0; mi < 4; ++mi) { Af[mi][0] = LDA(mi, 0); Af[mi][1] = LDA(mi, 1); }
#pragma unroll
        for (int ni = 0; ni < 2; ++ni) { Bf[ni][0] = LDB(ni, 0); Bf[ni][1] = LDB(ni, 1); }
        __builtin_amdgcn_sched_barrier(0);
        if (Hb < NHALF) stage_H(Hb);
        BAR();
        __builtin_amdgcn_s_setprio(1);
#pragma unroll
        for (int kb = 0; kb < 2; ++kb)
#pragma unroll
            for (int mi = 0; mi < 4; ++mi)
#pragma unroll
                for (int ni = 0; ni < 2; ++ni)
                    acc[mi][ni] = __builtin_amdgcn_mfma_f32_16x16x32_bf16(Af[mi][kb], Bf[ni][kb], acc[mi][ni], 0, 0, 0);
        __builtin_amdgcn_s_setprio(0);
        BAR();

        // -- phase 1: read A mi4-7 (8 ds_read); stage (t+2,A0); MFMA Q1
#pragma unroll
        for (int mi = 4; mi < 8; ++mi) { Af[mi][0] = LDA(mi, 0); Af[mi][1] = LDA(mi, 1); }
        __builtin_amdgcn_sched_barrier(0);
        if (Hb + 1 < NHALF) stage_H(Hb + 1);
        BAR();
        __builtin_amdgcn_s_setprio(1);
#pragma unroll
        for (int kb = 0; kb < 2; ++kb)
#pragma unroll
            for (int mi = 4; mi < 8; ++mi)
#pragma unroll
                for (int ni = 0; ni < 2; ++ni)
                    acc[mi][ni] = __builtin_amdgcn_mfma_f32_16x16x32_bf16(Af[mi][kb], Bf[ni][kb], acc[mi][ni], 0, 0, 0);
        __builtin_amdgcn_s_setprio(0);
        BAR();

        // -- phase 2: read B ni2-3 (4 ds_read, overwrite Bf); stage (t+2,A1); MFMA Q2
#pragma unroll
        for (int ni = 0; ni < 2; ++ni) { Bf[ni][0] = LDB(ni + 2, 0); Bf[ni][1] = LDB(ni + 2, 1); }
        __builtin_amdgcn_sched_barrier(0);
        if (Hb + 2 < NHALF) stage_H(Hb + 2);
        BAR();
        __builtin_amdgcn_s_setprio(1);
#pragma unroll
        for (int kb = 0; kb < 2; ++kb)
#pragma unroll
            for (int mi = 0; mi < 4; ++mi)
#pragma unroll
                for (int nj = 0; nj < 2; ++nj)
                    acc[mi][nj + 2] = __builtin_amdgcn_mfma_f32_16x16x32_bf16(Af[mi][kb], Bf[nj][kb], acc[mi][nj + 2], 0, 0, 0);
        __builtin_amdgcn_s_setprio(0);
        BAR();

        // -- phase 3: no ds_read; stage (t+2,B0); MFMA Q3; counted vmcnt; bar
        if (Hb + 3 < NHALF) stage_H(Hb + 3);
        BAR();
        __builtin_amdgcn_s_setprio(1);
#pragma unroll
        for (int kb = 0; kb < 2; ++kb)
#pragma unroll
            for (int mi = 4; mi < 8; ++mi)
#pragma unroll
                for (int nj = 0; nj < 2; ++nj)
                    acc[mi][nj + 2] = __builtin_amdgcn_mfma_f32_16x16x32_bf16(Af[mi][kb], Bf[nj][kb], acc[mi][nj + 2], 0, 0, 0);
        __builtin_amdgcn_s_setprio(0);
        if (t < NT - 2)       asm volatile("s_waitcnt vmcnt(6)" ::: "memory"); // tile t+1 landed, 3 halves in flight
        else if (t == NT - 2) asm volatile("s_waitcnt vmcnt(0)" ::: "memory"); // final drain
        BAR();
    }

    // epilogue: C/D layout col=lane&15, row=(lane>>4)*4+reg
#pragma unroll
    for (int mi = 0; mi < 8; ++mi)
#pragma unroll
        for (int ni = 0; ni < 4; ++ni) {
            const int col = nBase + wn * 64 + ni * 16 + lr;
#pragma unroll
            for (int r = 0; r < 4; ++r) {
                const int row = mBase + wm * 128 + mi * 16 + (lane >> 4) * 4 + r;
                C[(size_t)row * N_DIM + col] = (float)(__bf16)acc[mi][ni][r];
            }
        }
#undef LDA
#undef LDB
}

extern "C" void kernel_launch(void* const* d_in, const int* in_sizes, int n_in,
                              void* d_out, int out_size, void* d_ws, size_t ws_size,
                              hipStream_t stream)
{
    const float* x       = (const float*)d_in[0];
    const int*   qweight = (const int*)d_in[1];
    const float* qscale  = (const float*)d_in[2];
    const int*   qzeros  = (const int*)d_in[3];
    float*       out     = (float*)d_out;

    __bf16* W  = (__bf16*)d_ws;
    __bf16* xb = (__bf16*)((char*)d_ws + (size_t)N_DIM * K_DIM * sizeof(__bf16));

    {
        int total = OUT_F * PACKED;
        dequant_kernel<<<(total + 255) / 256, 256, 0, stream>>>(qweight, qscale, qzeros, W);
    }
    {
        int n8 = (M_DIM * K_DIM) / 8;
        cvt_kernel<<<(n8 + 255) / 256, 256, 0, stream>>>(x, xb, n8);
    }
    {
        // 128 KiB dynamic LDS opt-in (no-op on ROCm builds that don't need it)
        (void)hipFuncSetAttribute((const void*)gemm_kernel,
                                  hipFuncAttributeMaxDynamicSharedMemorySize, 131072);
        dim3 grid((M_DIM / BM) * (N_DIM / BN));   // 512 blocks
        gemm_kernel<<<grid, 512, 131072, stream>>>(xb, W, out);
    }
}